// Round 6
// baseline (345.614 us; speedup 1.0000x reference)
//
#include <hip/hip_runtime.h>
#include <cstdint>
#include <cstddef>

// Problem constants
#define BB   2
#define SS   1024
#define HID  2048
#define HH   32
#define KVHH 8
#define DD   64
#define NQKV 3072   // fused QKV projection width: 2048 q + 512 k + 512 v
#define QKW  2560   // qk_bf row width: 2048 q + 512 k

typedef __attribute__((ext_vector_type(8))) short bf16x8;
typedef __attribute__((ext_vector_type(4))) float f32x4;

__device__ __forceinline__ unsigned short f2bf(float f) {
    unsigned int u = __float_as_uint(f);
    unsigned int r = (u + 0x7fffu + ((u >> 16) & 1u)) >> 16;
    return (unsigned short)r;
}

// async global->LDS 16B (wave-uniform LDS base + lane*16 layout required)
__device__ __forceinline__ void g2l16(const unsigned short* g, unsigned short* l) {
    __builtin_amdgcn_global_load_lds(
        (__attribute__((address_space(1))) void*)(unsigned short*)g,
        (__attribute__((address_space(3))) void*)l,
        16, 0, 0);
}

// ---------------------------------------------------------------------------
// prep: z=0..3 weight transpose+convert; z=4 hidden fp32->bf16.
// ---------------------------------------------------------------------------
__global__ void prep(const float* __restrict__ hidden,
                     const float* __restrict__ Wq, const float* __restrict__ Wk,
                     const float* __restrict__ Wv, const float* __restrict__ Wo,
                     unsigned short* __restrict__ hidden_bf,
                     unsigned short* __restrict__ WqkvT,
                     unsigned short* __restrict__ WoT)
{
    const int z  = blockIdx.z;
    const int tx = threadIdx.x, ty = threadIdx.y;

    if (z == 4) {
        int r0 = blockIdx.y * 32, c0 = blockIdx.x * 32;
        #pragma unroll
        for (int i = 0; i < 4; ++i) {
            int row = r0 + ty * 4 + i;
            hidden_bf[(size_t)row * 2048 + c0 + tx] =
                f2bf(hidden[(size_t)row * 2048 + c0 + tx]);
        }
        return;
    }

    const float* W;
    unsigned short* Wt;
    int N;
    if (z == 0)      { W = Wq; Wt = WqkvT;                        N = 2048; }
    else if (z == 1) { W = Wk; Wt = WqkvT + (size_t)2048 * 2048;  N = 512;  }
    else if (z == 2) { W = Wv; Wt = WqkvT + (size_t)2560 * 2048;  N = 512;  }
    else             { W = Wo; Wt = WoT;                          N = 2048; }
    if (blockIdx.x * 32 >= N) return;

    __shared__ float t[32][33];
    const int n0 = blockIdx.x * 32, k0 = blockIdx.y * 32;
    #pragma unroll
    for (int i = 0; i < 4; ++i)
        t[ty * 4 + i][tx] = W[(size_t)(k0 + ty * 4 + i) * N + n0 + tx];
    __syncthreads();
    #pragma unroll
    for (int i = 0; i < 4; ++i)
        Wt[(size_t)(n0 + ty * 4 + i) * 2048 + k0 + tx] = f2bf(t[tx][ty * 4 + i]);
}

// ---------------------------------------------------------------------------
// bf16 MFMA GEMM, B-transposed, async global_load_lds staging (m97 pattern).
// C(MxN fp32) = A(MxK bf16) @ Bt(NxK bf16)^T. 128x128 tile, BK=32.
// ---------------------------------------------------------------------------
__global__ __launch_bounds__(256) void gemm_bf16_bt(
    const unsigned short* __restrict__ A,
    const unsigned short* __restrict__ Bt,
    float* __restrict__ C, int M, int N, int K)
{
    __shared__ short As[128][32];
    __shared__ short Bs[128][32];

    const int tid  = threadIdx.x;
    const int lane = tid & 63;
    const int wave = tid >> 6;
    const int wm = (wave >> 1) * 64, wn = (wave & 1) * 64;
    const int m0 = blockIdx.y * 128, n0 = blockIdx.x * 128;

    f32x4 acc[4][4] = {};

    const int mrow = lane & 15;
    const int kq   = (lane >> 4) * 8;

    for (int k0 = 0; k0 < K; k0 += 32) {
        #pragma unroll
        for (int p = 0; p < 2; ++p) {
            int ci = tid + p * 256;           // 0..511, lane-contiguous per wave
            int row = ci >> 2;
            int q = (ci & 3) * 8;
            g2l16(&A [(size_t)(m0 + row) * K + k0 + q], (unsigned short*)&As[0][0] + ci * 8);
            g2l16(&Bt[(size_t)(n0 + row) * K + k0 + q], (unsigned short*)&Bs[0][0] + ci * 8);
        }
        __syncthreads();

        bf16x8 af[4], bfr[4];
        #pragma unroll
        for (int i = 0; i < 4; ++i)
            af[i] = *(const bf16x8*)&As[wm + i * 16 + mrow][kq];
        #pragma unroll
        for (int j = 0; j < 4; ++j)
            bfr[j] = *(const bf16x8*)&Bs[wn + j * 16 + mrow][kq];

        #pragma unroll
        for (int i = 0; i < 4; ++i)
            #pragma unroll
            for (int j = 0; j < 4; ++j)
                acc[i][j] = __builtin_amdgcn_mfma_f32_16x16x32_bf16(
                    af[i], bfr[j], acc[i][j], 0, 0, 0);
        __syncthreads();
    }

    #pragma unroll
    for (int i = 0; i < 4; ++i) {
        int grow = m0 + wm + i * 16 + (lane >> 4) * 4;
        #pragma unroll
        for (int j = 0; j < 4; ++j) {
            int gcol = n0 + wn + j * 16 + (lane & 15);
            #pragma unroll
            for (int rg = 0; rg < 4; ++rg)
                C[(size_t)(grow + rg) * N + gcol] = acc[i][j][rg];
        }
    }
}

// ---------------------------------------------------------------------------
// postproc: { rope q/k -> qk_bf bf16 } + { v transpose -> v_t bf16 }.
// ---------------------------------------------------------------------------
__global__ void postproc(const float* __restrict__ qkv,
                         unsigned short* __restrict__ qk_bf,
                         unsigned short* __restrict__ v_t)
{
    const int gb = blockIdx.x;
    if (gb < 10240) {
        const int r = gb >> 8;
        const int t = threadIdx.x & 31;
        const int row = (gb & 255) * 8 + (threadIdx.x >> 5);
        const int s = row & (SS - 1);

        const float* src = qkv + (size_t)row * NQKV + r * 64;
        unsigned short* dst = qk_bf + (size_t)row * QKW + r * 64;

        float x1 = src[t];
        float x2 = src[t + 32];
        float inv = powf(10000.f, -(float)t * (1.f / 32.f));
        float ang = (float)s * inv;
        float c, sn;
        sincosf(ang, &sn, &c);
        float scale = (r < 32) ? 0.125f : 1.0f;
        dst[t]      = f2bf((x1 * c - x2 * sn) * scale);
        dst[t + 32] = f2bf((x2 * c + x1 * sn) * scale);
    } else {
        __shared__ float tls[32][33];
        const int id = gb - 10240;
        const int cblk = id & 15;
        const int sblk = (id >> 4) & 31;
        const int b    = id >> 9;
        const int c0 = cblk * 32, s0 = sblk * 32;
        const int tx = threadIdx.x & 31, ty = threadIdx.x >> 5;
        #pragma unroll
        for (int i = 0; i < 4; ++i)
            tls[ty * 4 + i][tx] =
                qkv[(size_t)(b * SS + s0 + ty * 4 + i) * NQKV + 2560 + c0 + tx];
        __syncthreads();
        #pragma unroll
        for (int i = 0; i < 4; ++i)
            v_t[(size_t)(b * 512 + c0 + ty * 4 + i) * SS + s0 + tx] =
                f2bf(tls[tx][ty * 4 + i]);
    }
}

// ---------------------------------------------------------------------------
// Chunk decode: blockIdx.x in [0,40): big-qt first. Returns (qt, chunk).
// nchunk(qt) = ceil((qt+1)/4); sum over qt=0..15 is 40.
// ---------------------------------------------------------------------------
__device__ __forceinline__ void decode_chunk(int bx, int& qt, int& c) {
    int x = 39 - bx;
    int t = 0, acc = 0;
    for (;;) { int n = (t + 4) >> 2; if (x < acc + n) break; acc += n; ++t; }
    qt = t; c = x - acc;
}

// ---------------------------------------------------------------------------
// attn_l: partial softmax denominators per k-chunk (4 k-tiles of 64).
// Grid (40, 8 kh, 2 b); block 256 = 4 waves = 4 heads of the GQA group.
// Writes l_part[((b*32+h)*4 + chunk)*1024 + q] (each slot written once).
// Also zeroes AO_f32 (runs strictly before attn_o).
// ---------------------------------------------------------------------------
__global__ __launch_bounds__(256) void attn_l(
    const unsigned short* __restrict__ qk_bf,
    const float* __restrict__ bias_diag,
    float* __restrict__ l_part,
    float* __restrict__ AO_f32)
{
    {   // zero a slice of AO_f32 (2048*2048 floats = 1048576 float4)
        int linear = ((int)blockIdx.z * 8 + (int)blockIdx.y) * 40 + (int)blockIdx.x;
        size_t base4 = (size_t)linear * 1639 + threadIdx.x;
        float4 z = make_float4(0.f, 0.f, 0.f, 0.f);
        #pragma unroll
        for (int i = 0; i < 7; ++i) {
            size_t p4 = base4 + (size_t)i * 256;
            if (p4 < (size_t)1048576) ((float4*)AO_f32)[p4] = z;
        }
    }

    int qt, c;
    decode_chunk(blockIdx.x, qt, c);
    const int kh = blockIdx.y, b = blockIdx.z;
    const int wave = threadIdx.x >> 6, lane = threadIdx.x & 63;
    const int quad = lane >> 4, l15 = lane & 15;
    const int h  = kh * 4 + wave;
    const int q0 = qt * 64;
    const int j0 = c * 4;
    const int j1 = (j0 + 4 < qt + 1) ? j0 + 4 : qt + 1;
    const int kbase = j0 * 64;
    const int rmin  = q0 - kbase - 255;

    __shared__ float bdw_all[4][320];
    float* bdw = bdw_all[wave];
    for (int i = lane; i < 320; i += 64) {
        int rel = rmin + i;
        bdw[i] = ((unsigned)rel < 1024u) ? bias_diag[h * 1024 + rel] : 0.f;
    }

    bf16x8 Qf[4][2];
    const unsigned short* Qg = qk_bf + (size_t)(b * SS + q0) * QKW + h * 64;
    #pragma unroll
    for (int nq = 0; nq < 4; ++nq)
        #pragma unroll
        for (int s = 0; s < 2; ++s)
            Qf[nq][s] = *(const bf16x8*)&Qg[(size_t)(nq * 16 + l15) * QKW + s * 32 + quad * 8];

    const unsigned short* Kg = qk_bf + (size_t)(b * SS) * QKW + 2048 + kh * 64;

    float lp[4] = {0.f, 0.f, 0.f, 0.f};
    for (int j = j0; j < j1; ++j) {
        const int k0 = j * 64;
        bf16x8 Kf[4][2];
        #pragma unroll
        for (int nk = 0; nk < 4; ++nk)
            #pragma unroll
            for (int s = 0; s < 2; ++s)
                Kf[nk][s] = *(const bf16x8*)&Kg[(size_t)(k0 + nk * 16 + l15) * QKW + s * 32 + quad * 8];

        f32x4 st[4][4] = {};   // [nk][nq]: S^T tile, col q = l15, row kp
        #pragma unroll
        for (int s = 0; s < 2; ++s)
            #pragma unroll
            for (int nk = 0; nk < 4; ++nk)
                #pragma unroll
                for (int nq = 0; nq < 4; ++nq)
                    st[nk][nq] = __builtin_amdgcn_mfma_f32_16x16x32_bf16(
                        Kf[nk][s], Qf[nq][s], st[nk][nq], 0, 0, 0);

        const bool full = (j < qt);
        #pragma unroll
        for (int nk = 0; nk < 4; ++nk)
            #pragma unroll
            for (int nq = 0; nq < 4; ++nq) {
                int relb = (q0 + nq * 16 + l15) - (k0 + nk * 16 + quad * 4);
                #pragma unroll
                for (int r = 0; r < 4; ++r) {
                    int rel = relb - r;
                    if (full || rel >= 0)
                        lp[nq] += __expf(st[nk][nq][r] + bdw[rel - rmin]);
                }
            }
    }

    // butterfly over the 4 quads; then quad 0 stores
    #pragma unroll
    for (int nq = 0; nq < 4; ++nq) {
        lp[nq] += __shfl_xor(lp[nq], 16, 64);
        lp[nq] += __shfl_xor(lp[nq], 32, 64);
    }
    if (quad == 0) {
        #pragma unroll
        for (int nq = 0; nq < 4; ++nq)
            l_part[(size_t)((b * 32 + h) * 4 + c) * 1024 + q0 + nq * 16 + l15] = lp[nq];
    }
}

// ---------------------------------------------------------------------------
// attn_o: recompute scores for the chunk, w = relu(exp(s+bias) - c*l),
// PV via MFMA, scale by 1/l, atomicAdd into AO_f32.
// ---------------------------------------------------------------------------
__global__ __launch_bounds__(256) void attn_o(
    const unsigned short* __restrict__ qk_bf,
    const unsigned short* __restrict__ v_t,
    const float* __restrict__ bias_diag,
    const float* __restrict__ soff,
    const float* __restrict__ l_part,
    float* __restrict__ AO_f32)
{
    int qt, c;
    decode_chunk(blockIdx.x, qt, c);
    const int kh = blockIdx.y, b = blockIdx.z;
    const int wave = threadIdx.x >> 6, lane = threadIdx.x & 63;
    const int quad = lane >> 4, l15 = lane & 15;
    const int h  = kh * 4 + wave;
    const int q0 = qt * 64;
    const int j0 = c * 4;
    const int j1 = (j0 + 4 < qt + 1) ? j0 + 4 : qt + 1;
    const int kbase = j0 * 64;
    const int rmin  = q0 - kbase - 255;
    const int nch   = (qt + 4) >> 2;

    // Ws: wave-private P-tile bounce, 64 q x 64 k. Row stride 72 shorts
    // (144 B): 4-bank row skew -> only free 2-way aliasing on b128 reads.
    // (R5 bug: stride 40 < 64 columns -> overflow garbage. Keep >= 64 + pad.)
    __shared__ short Ws_all[4][64][72];
    __shared__ float bdw_all[4][320];
    short (*Ws)[72] = Ws_all[wave];
    float* bdw = bdw_all[wave];
    for (int i = lane; i < 320; i += 64) {
        int rel = rmin + i;
        bdw[i] = ((unsigned)rel < 1024u) ? bias_diag[h * 1024 + rel] : 0.f;
    }

    bf16x8 Qf[4][2];
    const unsigned short* Qg = qk_bf + (size_t)(b * SS + q0) * QKW + h * 64;
    #pragma unroll
    for (int nq = 0; nq < 4; ++nq)
        #pragma unroll
        for (int s = 0; s < 2; ++s)
            Qf[nq][s] = *(const bf16x8*)&Qg[(size_t)(nq * 16 + l15) * QKW + s * 32 + quad * 8];

    // total l per q-row (sum of this qt's chunk slots), then invl / c*l
    float invl[4], cl[4];
    {
        float offa = fabsf(soff[h] + 1.f);
        #pragma unroll
        for (int nq = 0; nq < 4; ++nq) {
            int q = q0 + nq * 16 + l15;
            float s = 0.f;
            for (int cc = 0; cc < nch; ++cc)
                s += l_part[(size_t)((b * 32 + h) * 4 + cc) * 1024 + q];
            invl[nq] = 1.f / s;
            cl[nq] = offa / (float)(q + 1) * s;
        }
    }

    const unsigned short* Kg = qk_bf + (size_t)(b * SS) * QKW + 2048 + kh * 64;
    const unsigned short* Vg = v_t + (size_t)(b * 512 + kh * 64) * SS;

    f32x4 Oa[4][4] = {};       // [nq][nd]
    for (int j = j0; j < j1; ++j) {
        const int k0 = j * 64;
        bf16x8 Kf[4][2], Vf[4][2];
        #pragma unroll
        for (int nk = 0; nk < 4; ++nk)
            #pragma unroll
            for (int s = 0; s < 2; ++s)
                Kf[nk][s] = *(const bf16x8*)&Kg[(size_t)(k0 + nk * 16 + l15) * QKW + s * 32 + quad * 8];
        #pragma unroll
        for (int nd = 0; nd < 4; ++nd)
            #pragma unroll
            for (int cc = 0; cc < 2; ++cc)
                Vf[nd][cc] = *(const bf16x8*)&Vg[(size_t)(nd * 16 + l15) * SS + k0 + cc * 32 + quad * 8];

        f32x4 st[4][4] = {};
        #pragma unroll
        for (int s = 0; s < 2; ++s)
            #pragma unroll
            for (int nk = 0; nk < 4; ++nk)
                #pragma unroll
                for (int nq = 0; nq < 4; ++nq)
                    st[nk][nq] = __builtin_amdgcn_mfma_f32_16x16x32_bf16(
                        Kf[nk][s], Qf[nq][s], st[nk][nq], 0, 0, 0);

        // w -> Ws (wave-private, packed 4-wide b64 stores)
        const bool full = (j < qt);
        #pragma unroll
        for (int nk = 0; nk < 4; ++nk)
            #pragma unroll
            for (int nq = 0; nq < 4; ++nq) {
                int relb = (q0 + nq * 16 + l15) - (k0 + nk * 16 + quad * 4);
                ushort4 pk;
                #pragma unroll
                for (int r = 0; r < 4; ++r) {
                    int rel = relb - r;
                    float w = 0.f;
                    if (full || rel >= 0)
                        w = fmaxf(__expf(st[nk][nq][r] + bdw[rel - rmin]) - cl[nq], 0.f);
                    ((unsigned short*)&pk)[r] = f2bf(w);
                }
                *(ushort4*)&Ws[nq * 16 + l15][nk * 16 + quad * 4] = pk;
            }

        // PV: A = Ws rows (m=q), B = Vt rows (n=d), contraction over local k
        #pragma unroll
        for (int cc = 0; cc < 2; ++cc) {
            bf16x8 Wf[4];
            #pragma unroll
            for (int nq = 0; nq < 4; ++nq)
                Wf[nq] = *(const bf16x8*)&Ws[nq * 16 + l15][cc * 32 + quad * 8];
            #pragma unroll
            for (int nq = 0; nq < 4; ++nq)
                #pragma unroll
                for (int nd = 0; nd < 4; ++nd)
                    Oa[nq][nd] = __builtin_amdgcn_mfma_f32_16x16x32_bf16(
                        Wf[nq], Vf[nd][cc], Oa[nq][nd], 0, 0, 0);
        }
    }

    // epilogue: scale by 1/l, atomic accumulate
    #pragma unroll
    for (int nq = 0; nq < 4; ++nq)
        #pragma unroll
        for (int r = 0; r < 4; ++r) {
            float iv = __shfl(invl[nq], quad * 4 + r, 64);
            int q = q0 + nq * 16 + quad * 4 + r;
            float* dst = &AO_f32[(size_t)(b * SS + q) * 2048 + h * 64 + l15];
            #pragma unroll
            for (int nd = 0; nd < 4; ++nd)
                atomicAdd(dst + nd * 16, Oa[nq][nd][r] * iv);
        }
}

// ---------------------------------------------------------------------------
// AO fp32 -> bf16
// ---------------------------------------------------------------------------
__global__ void conv_ao(const float* __restrict__ AO_f32,
                        unsigned short* __restrict__ AO_bf)
{
    int i = blockIdx.x * 256 + threadIdx.x;
    float4 v = ((const float4*)AO_f32)[i];
    ushort4 o;
    o.x = f2bf(v.x); o.y = f2bf(v.y); o.z = f2bf(v.z); o.w = f2bf(v.w);
    ((ushort4*)AO_bf)[i] = o;
}

// ---------------------------------------------------------------------------
extern "C" void kernel_launch(void* const* d_in, const int* in_sizes, int n_in,
                              void* d_out, int out_size, void* d_ws, size_t ws_size,
                              hipStream_t stream)
{
    const float* hidden    = (const float*)d_in[0];
    const float* Wq        = (const float*)d_in[2];
    const float* Wk        = (const float*)d_in[3];
    const float* Wv        = (const float*)d_in[4];
    const float* Wo        = (const float*)d_in[5];
    const float* bias_diag = (const float*)d_in[6];
    const float* soff      = (const float*)d_in[7];
    float* out = (float*)d_out;

    // Workspace aliasing (54.5 MB, proven footprint):
    //  A [0,20.97M): hidden_bf(8.39)+WqkvT(12.58) --dead after QKV gemm-->
    //                qk_bf[0,10.49M) + v_t[10.49M,12.58M) + AO_bf[12.58M,20.97M)
    //  B [20.97M,29.36M): WoT
    //  C [29.36M,54.53M): qkv fp32(25.17M) --dead after postproc-->
    //                AO_f32[29.36M,46.14M) + l_part[46.14M,47.19M)
    char* wsb = (char*)d_ws;
    unsigned short* hidden_bf = (unsigned short*)wsb;
    unsigned short* WqkvT     = (unsigned short*)(wsb + (size_t)8388608);
    unsigned short* qk_bf     = (unsigned short*)wsb;
    unsigned short* v_t       = (unsigned short*)(wsb + (size_t)10485760);
    unsigned short* AO_bf     = (unsigned short*)(wsb + (size_t)12582912);
    unsigned short* WoT       = (unsigned short*)(wsb + (size_t)20971520);
    float*          qkv       = (float*)(wsb + (size_t)29360128);
    float*          AO_f32    = (float*)(wsb + (size_t)29360128);
    float*          l_part    = (float*)(wsb + (size_t)46137344);

    // 1. weight transposes + hidden convert
    prep<<<dim3(64, 64, 5), dim3(32, 8), 0, stream>>>(
        hidden, Wq, Wk, Wv, Wo, hidden_bf, WqkvT, WoT);

    // 2. fused QKV projection (fp32 out)
    gemm_bf16_bt<<<dim3(NQKV / 128, 2048 / 128), dim3(256), 0, stream>>>(
        hidden_bf, WqkvT, qkv, 2048, NQKV, 2048);

    // 3. rope+convert q,k and v transpose
    postproc<<<dim3(11264), dim3(256), 0, stream>>>(qkv, qk_bf, v_t);

    // 4. partial denominators (also zeroes AO_f32)
    attn_l<<<dim3(40, KVHH, BB), dim3(256), 0, stream>>>(
        qk_bf, bias_diag, l_part, AO_f32);

    // 5. PV accumulate
    attn_o<<<dim3(40, KVHH, BB), dim3(256), 0, stream>>>(
        qk_bf, v_t, bias_diag, soff, l_part, AO_f32);

    // 6. AO -> bf16
    conv_ao<<<dim3(4096), dim3(256), 0, stream>>>(AO_f32, AO_bf);

    // 7. output projection
    gemm_bf16_bt<<<dim3(2048 / 128, 2048 / 128), dim3(256), 0, stream>>>(
        AO_bf, WoT, out, 2048, 2048, 2048);
}